// Round 3
// baseline (5230.072 us; speedup 1.0000x reference)
//
#include <hip/hip_runtime.h>
#include <math.h>

#define RBF 32
#define BLOCK 256

// out[a,i] = sum_b cross(F1[a,b,:], L[b,:])_i
// F1[a,b,:] = unit(rij[a,b]) * radial[a,b]
// radial[a,b] = W2 . softplus(rbf[a,b,:] @ W1 + b1) + b2, masked if |rij|<1e-8
//
// Round-3 theory (re-run; round-2 bench was an infra failure, no data):
// round-1 fixed traffic (FETCH 4.4GB->287MB) but left the kernel
// latency-bound: 72KB LDS -> 2 blocks/CU -> 22% occupancy, serial
// stage->sync->compute. Each rbf row is exactly one 128B line consumed by
// exactly one thread, so LDS staging is pure overhead: load the row's 8
// float4 back-to-back into registers (same-line requests MSHR-merge -> one
// HBM fetch), register-double-buffer the next row, and drop sx entirely.
// LDS is now 4.7KB (weights only, wave-uniform broadcast reads), no
// per-tile barriers, occupancy capped by ~112 VGPRs at 4-5 waves/SIMD.
__global__ __launch_bounds__(BLOCK, 4)
void f1o1_kernel(const float* __restrict__ L,     // [N,3]
                 const float* __restrict__ rbf,   // [N,N,RBF]
                 const float* __restrict__ rij,   // [N,N,3]
                 const float* __restrict__ W1,    // [RBF,RBF]
                 const float* __restrict__ b1,    // [RBF]
                 const float* __restrict__ W2,    // [RBF]
                 const float* __restrict__ b2,    // [1]
                 float* __restrict__ out,         // [N,3]
                 int N)
{
    __shared__ float sW1[RBF * RBF];
    __shared__ float sb1[RBF];
    __shared__ float sW2[RBF];
    __shared__ float sred[4 * 3];

    const int t = threadIdx.x;
    const int a = blockIdx.x;

    for (int i = t; i < RBF * RBF; i += BLOCK) sW1[i] = W1[i];
    if (t < RBF) { sb1[t] = b1[t]; sW2[t] = W2[t]; }
    __syncthreads();   // only barrier before the final reduction

    const float bias2 = b2[0];
    float acc0 = 0.f, acc1 = 0.f, acc2 = 0.f;
    const size_t abase = (size_t)a * (size_t)N;

    // prologue: load row b = t (one 128B line per thread, 8 back-to-back float4)
    float4 cx[8];
    {
        const float4* rp = (const float4*)(rbf + (abase + (size_t)t) * RBF);
        #pragma unroll
        for (int q = 0; q < 8; ++q) cx[q] = rp[q];
    }

    for (int b = t; b < N; ) {
        const int bn = b + BLOCK;
        // prefetch next row while computing this one (register double-buffer)
        float4 nx[8];
        const bool have_next = (bn < N);
        if (have_next) {
            const float4* rp = (const float4*)(rbf + (abase + (size_t)bn) * RBF);
            #pragma unroll
            for (int q = 0; q < 8; ++q) nx[q] = rp[q];
        }

        // ---- h = b1 + x @ W1 (W1 from LDS, wave-uniform broadcast) ----
        float4 h[8];
        #pragma unroll
        for (int jq = 0; jq < 8; ++jq) h[jq] = ((const float4*)sb1)[jq];

        #pragma unroll
        for (int q = 0; q < 8; ++q) {
            const float xs[4] = {cx[q].x, cx[q].y, cx[q].z, cx[q].w};
            #pragma unroll
            for (int rr = 0; rr < 4; ++rr) {
                const float xv = xs[rr];
                const float4* w4 = (const float4*)(sW1 + (q * 4 + rr) * RBF);
                #pragma unroll
                for (int jq = 0; jq < 8; ++jq) {
                    const float4 w = w4[jq];
                    h[jq].x = fmaf(xv, w.x, h[jq].x);
                    h[jq].y = fmaf(xv, w.y, h[jq].y);
                    h[jq].z = fmaf(xv, w.z, h[jq].z);
                    h[jq].w = fmaf(xv, w.w, h[jq].w);
                }
            }
        }

        // ---- softplus + Dense2 ----
        float r = bias2;
        #pragma unroll
        for (int jq = 0; jq < 8; ++jq) {
            const float4 w2v = ((const float4*)sW2)[jq];
            const float hv[4] = {h[jq].x, h[jq].y, h[jq].z, h[jq].w};
            const float wv[4] = {w2v.x, w2v.y, w2v.z, w2v.w};
            #pragma unroll
            for (int c = 0; c < 4; ++c) {
                float v = hv[c];
                float sp = fmaxf(v, 0.f) + __logf(1.f + __expf(-fabsf(v)));
                r = fmaf(sp, wv[c], r);
            }
        }

        // ---- mask, unit vector, cross with L, accumulate ----
        {
            const float* rr3 = rij + (abase + (size_t)b) * 3;
            float r0 = rr3[0], r1 = rr3[1], r2 = rr3[2];
            float ss = r0 * r0 + r1 * r1 + r2 * r2;
            // dij < 1e-8  <=>  ss < 1e-16
            float scale = (ss < 1e-16f) ? 0.f : r * rsqrtf(fmaxf(ss, 1e-8f));
            float f0 = r0 * scale, f1 = r1 * scale, f2 = r2 * scale;
            const float* lp = L + (size_t)b * 3;
            float l0 = lp[0], l1 = lp[1], l2 = lp[2];
            acc0 += f1 * l2 - f2 * l1;
            acc1 += f2 * l0 - f0 * l2;
            acc2 += f0 * l1 - f1 * l0;
        }

        b = bn;
        if (have_next) {
            #pragma unroll
            for (int q = 0; q < 8; ++q) cx[q] = nx[q];
        }
    }

    // ---- wave reduction (64 lanes) + block reduction ----
    #pragma unroll
    for (int off = 32; off > 0; off >>= 1) {
        acc0 += __shfl_down(acc0, off, 64);
        acc1 += __shfl_down(acc1, off, 64);
        acc2 += __shfl_down(acc2, off, 64);
    }
    const int wv = t >> 6;
    if ((t & 63) == 0) {
        sred[wv * 3 + 0] = acc0;
        sred[wv * 3 + 1] = acc1;
        sred[wv * 3 + 2] = acc2;
    }
    __syncthreads();
    if (t < 3) {
        out[(size_t)a * 3 + t] = sred[t] + sred[3 + t] + sred[6 + t] + sred[9 + t];
    }
}

extern "C" void kernel_launch(void* const* d_in, const int* in_sizes, int n_in,
                              void* d_out, int out_size, void* d_ws, size_t ws_size,
                              hipStream_t stream) {
    const float* L   = (const float*)d_in[0];  // layer_input [N,1,3]
    const float* rbf = (const float*)d_in[1];  // rbf_inputs [N,N,32]
    const float* rij = (const float*)d_in[2];  // rij [N,N,3]
    const float* W1  = (const float*)d_in[3];
    const float* b1  = (const float*)d_in[4];
    const float* W2  = (const float*)d_in[5];
    const float* b2  = (const float*)d_in[6];
    float* out = (float*)d_out;

    const int N = in_sizes[0] / 3;  // 2048

    f1o1_kernel<<<N, BLOCK, 0, stream>>>(L, rbf, rij, W1, b1, W2, b2, out, N);
}